// Round 4
// baseline (422.025 us; speedup 1.0000x reference)
//
#include <hip/hip_runtime.h>

// HaloAttn on MI355X (gfx950). f32 in/out, bf16 MFMA internals.
// Pipeline (ws >= 101,466,112 B, proven available in round 3):
//   pos_proj:  PK [208][256] f32, PQ [64][256] f32
//   wtrans:    Wt4[mat][n][k] bf16 (transposed weights)
//   qkv_gemm:  XQpos = x@Wq + PQ (bf16), XK = x@Wk (bf16), XVt = (x@Wv)^T [ch][pix] (bf16)
//   halo:      one WG per (window, head): stage K(+PK)/Vt/Q, QK^T, softmax, PV -> XO (aliases XQ)
//   out_proj:  out = XO @ Wp + bias (f32)

using bf16x8 = __attribute__((ext_vector_type(8))) short;
using f32x4  = __attribute__((ext_vector_type(4))) float;

__device__ __forceinline__ float bf2f(unsigned short u) {
  return __uint_as_float(((unsigned int)u) << 16);
}
__device__ __forceinline__ unsigned short f2bf(float f) {
  unsigned int x = __float_as_uint(f);
  x += 0x7fffu + ((x >> 16) & 1u);
  return (unsigned short)(x >> 16);
}
__device__ __forceinline__ unsigned int pack2(float a, float b) {
  return (unsigned int)f2bf(a) | ((unsigned int)f2bf(b) << 16);
}
__device__ __forceinline__ int div14(int p) { return (p * 4682) >> 16; }  // valid p < ~5000

// ---------------- pos_proj ----------------
__global__ __launch_bounds__(256) void pos_proj_kernel(
    const float* __restrict__ Wq, const float* __restrict__ Wk,
    float* __restrict__ PK, float* __restrict__ PQ) {
  __shared__ float pr[256];
  const int row = blockIdx.x, o = threadIdx.x;
  const float* Wm;
  float* dst;
  int ii, jj;
  if (row < 208) {
    if (row >= 196) { PK[row * 256 + o] = 0.f; return; }
    ii = row / 14; jj = row % 14;
    Wm = Wk; dst = PK + row * 256;
  } else {
    int qp = row - 208;
    ii = (qp >> 3) + 3; jj = (qp & 7) + 3;
    Wm = Wq; dst = PQ + qp * 256;
  }
  const int cl = o & 127, mfreq = cl >> 1;
  float t = powf(10000.f, (float)mfreq * (1.f / 64.f));
  float base = (o < 128) ? (float)(ii + 1) : (float)(jj + 1);
  float arg = base * (6.283185307179586f / 14.000001f) / t;
  pr[o] = (cl & 1) ? cosf(arg) : sinf(arg);
  __syncthreads();
  float acc = 0.f;
  for (int c = 0; c < 256; ++c) acc = fmaf(pr[c], Wm[c * 256 + o], acc);
  dst[o] = acc;
}

// ---------------- wtrans ----------------
__global__ __launch_bounds__(256) void wtrans_kernel(
    const float* __restrict__ Wq, const float* __restrict__ Wk,
    const float* __restrict__ Wv, const float* __restrict__ Wp,
    unsigned short* __restrict__ Wt4) {
  const int mat = blockIdx.x >> 8, n = blockIdx.x & 255, k = threadIdx.x;
  const float* src = (mat == 0) ? Wq : (mat == 1) ? Wk : (mat == 2) ? Wv : Wp;
  Wt4[((mat * 256 + n) << 8) + k] = f2bf(src[k * 256 + n]);
}

// ---------------- qkv_gemm: grid (3, 512); mat fastest for x L2 reuse ----------------
__global__ __launch_bounds__(256, 2) void qkv_gemm_kernel(
    const float* __restrict__ xg, const unsigned short* __restrict__ Wt4,
    const float* __restrict__ PQ,
    unsigned short* __restrict__ XQ, unsigned short* __restrict__ XK,
    unsigned short* __restrict__ XVt) {
  __shared__ unsigned short sA[128 * 72];
  const int mat = blockIdx.x, m0 = blockIdx.y << 7;
  const unsigned short* Wt = Wt4 + (mat << 16);
  const int tid = threadIdx.x;
  const int wave = tid >> 6, lane = tid & 63, q = lane >> 4, r = lane & 15;

  f32x4 acc[2][16];
#pragma unroll
  for (int mt = 0; mt < 2; ++mt)
#pragma unroll
    for (int nt = 0; nt < 16; ++nt) acc[mt][nt] = (f32x4){0.f, 0.f, 0.f, 0.f};

  for (int cc = 0; cc < 4; ++cc) {
    __syncthreads();
    for (int t = tid; t < 1024; t += 256) {
      int row = t >> 3, seg = t & 7;
      const float* src = xg + ((m0 + row) << 8) + cc * 64 + seg * 8;
      float4 f0 = *(const float4*)(src);
      float4 f1 = *(const float4*)(src + 4);
      uint4 w;
      w.x = pack2(f0.x, f0.y); w.y = pack2(f0.z, f0.w);
      w.z = pack2(f1.x, f1.y); w.w = pack2(f1.z, f1.w);
      *(uint4*)&sA[row * 72 + seg * 8] = w;
    }
    __syncthreads();
#pragma unroll
    for (int kk = 0; kk < 2; ++kk) {
      const int k0 = cc * 64 + kk * 32;
      bf16x8 a0 = *(const bf16x8*)&sA[(wave * 32 + r) * 72 + kk * 32 + q * 8];
      bf16x8 a1 = *(const bf16x8*)&sA[(wave * 32 + 16 + r) * 72 + kk * 32 + q * 8];
#pragma unroll
      for (int nt = 0; nt < 16; ++nt) {
        bf16x8 bw = *(const bf16x8*)&Wt[((nt * 16 + r) << 8) + k0 + q * 8];
        acc[0][nt] = __builtin_amdgcn_mfma_f32_16x16x32_bf16(a0, bw, acc[0][nt], 0, 0, 0);
        acc[1][nt] = __builtin_amdgcn_mfma_f32_16x16x32_bf16(a1, bw, acc[1][nt], 0, 0, 0);
      }
    }
  }
  if (mat == 2) {  // transposed store: XVt[col][row]
#pragma unroll
    for (int mt = 0; mt < 2; ++mt)
#pragma unroll
      for (int nt = 0; nt < 16; ++nt) {
        int row0 = m0 + wave * 32 + mt * 16 + q * 4;
        short4 v4;
        v4.x = (short)f2bf(acc[mt][nt][0]); v4.y = (short)f2bf(acc[mt][nt][1]);
        v4.z = (short)f2bf(acc[mt][nt][2]); v4.w = (short)f2bf(acc[mt][nt][3]);
        *(short4*)&XVt[((nt * 16 + r) << 16) + row0] = v4;
      }
  } else {
    unsigned short* dst = (mat == 0) ? XQ : XK;
#pragma unroll
    for (int mt = 0; mt < 2; ++mt)
#pragma unroll
      for (int nt = 0; nt < 16; ++nt)
#pragma unroll
        for (int g = 0; g < 4; ++g) {
          int row = m0 + wave * 32 + mt * 16 + q * 4 + g;
          float v = acc[mt][nt][g];
          if (mat == 0)
            v += PQ[((((row >> 7) & 7) * 8 + (row & 7)) << 8) + nt * 16 + r];
          dst[(row << 8) + nt * 16 + r] = f2bf(v);
        }
  }
}

// ---------------- halo: one WG per (window, head); grid 8192 ----------------
// LDS strides chosen so 16-lane frag reads are <=2-way bank aliased (free):
//   sK stride 40 (20 dw), sVt stride 232 (116 dw ≡ 20), sU stride 40. All b128 16B-aligned.
struct alignas(16) SMH {
  unsigned short sK[196 * 40];   // K_h [p][32]; MFMA reads rows up to 223 spill into sVt (masked)
  unsigned short sVt[32 * 232];  // V_h^T [ch][p]; cols 196..231 zeroed
  unsigned short sU[64 * 40];    // union: Q_h then P-chunk then O_h (wave-private row reuse)
};

__global__ __launch_bounds__(256, 4) void halo_kernel(
    const unsigned short* XQ,           // no __restrict__: aliases XO
    const unsigned short* __restrict__ XK,
    const unsigned short* __restrict__ XVt,
    const float* __restrict__ PK,
    unsigned short* XO) {
  __shared__ SMH sm;
  const int wid = blockIdx.x;
  const int h = wid & 7, win = wid >> 3;
  const int b = win >> 8, widx = win & 255;
  const int wy = widx >> 4, wx = widx & 15;
  const int hc = h * 32;
  const int tid = threadIdx.x;
  const int wave = tid >> 6, lane = tid & 63, q = lane >> 4, r = lane & 15;
  const bool interior = (unsigned)(wy - 1) < 14u && (unsigned)(wx - 1) < 14u;
  const int ybase = wy * 8 - 3, xbase = wx * 8 - 3;
  constexpr float SCALE = 0.17677669529663687f;

  // zero sVt pad cols 196..231
  for (int idx = tid; idx < 1152; idx += 256) {
    int rr = idx / 36, c2 = idx - rr * 36;
    sm.sVt[rr * 232 + 196 + c2] = 0;
  }

  if (interior) {
    // ---- K = XK + PK (no validity checks) ----
    for (int t = tid; t < 784; t += 256) {
      int p = t >> 2, seg = t & 3;
      int i = div14(p), j = p - i * 14;
      int pix = (b * 128 + ybase + i) * 128 + xbase + j;
      bf16x8 kv = *(const bf16x8*)&XK[(pix << 8) + hc + seg * 8];
      const float4* pk4 = (const float4*)(PK + (p << 8) + hc + seg * 8);
      float4 f0 = pk4[0], f1 = pk4[1];
      uint4 w;
      w.x = pack2(bf2f((unsigned short)kv[0]) + f0.x, bf2f((unsigned short)kv[1]) + f0.y);
      w.y = pack2(bf2f((unsigned short)kv[2]) + f0.z, bf2f((unsigned short)kv[3]) + f0.w);
      w.z = pack2(bf2f((unsigned short)kv[4]) + f1.x, bf2f((unsigned short)kv[5]) + f1.y);
      w.w = pack2(bf2f((unsigned short)kv[6]) + f1.z, bf2f((unsigned short)kv[7]) + f1.w);
      *(uint4*)&sm.sK[p * 40 + seg * 8] = w;
    }
    // ---- Vt rows: 14 contiguous pixels; dword loads at even base + 16-bit shift ----
    for (int t = tid; t < 448; t += 256) {
      int c = div14(t), i = t - c * 14;
      int pix0 = (b * 128 + ybase + i) * 128 + xbase;  // odd; pix0-1 even -> 4B aligned
      const unsigned int* src = (const unsigned int*)(XVt + ((hc + c) << 16) + pix0 - 1);
      unsigned int d[8];
#pragma unroll
      for (int k = 0; k < 8; ++k) d[k] = src[k];
      int base = c * 232 + i * 14;
#pragma unroll
      for (int k = 0; k < 7; ++k)
        *(unsigned int*)&sm.sVt[base + k * 2] = (d[k] >> 16) | (d[k + 1] << 16);
    }
  } else {
    // ---- border: masked K ----
    for (int t = tid; t < 784; t += 256) {
      int p = t >> 2, seg = t & 3;
      int i = div14(p), j = p - i * 14;
      int y = ybase + i, x = xbase + j;
      uint4 w = {0u, 0u, 0u, 0u};
      if ((unsigned)y < 128u && (unsigned)x < 128u) {
        int pix = (b * 128 + y) * 128 + x;
        bf16x8 kv = *(const bf16x8*)&XK[(pix << 8) + hc + seg * 8];
        const float4* pk4 = (const float4*)(PK + (p << 8) + hc + seg * 8);
        float4 f0 = pk4[0], f1 = pk4[1];
        w.x = pack2(bf2f((unsigned short)kv[0]) + f0.x, bf2f((unsigned short)kv[1]) + f0.y);
        w.y = pack2(bf2f((unsigned short)kv[2]) + f0.z, bf2f((unsigned short)kv[3]) + f0.w);
        w.z = pack2(bf2f((unsigned short)kv[4]) + f1.x, bf2f((unsigned short)kv[5]) + f1.y);
        w.w = pack2(bf2f((unsigned short)kv[6]) + f1.z, bf2f((unsigned short)kv[7]) + f1.w);
      }
      *(uint4*)&sm.sK[p * 40 + seg * 8] = w;
    }
    // ---- border: masked Vt (scalar) ----
    for (int t = tid; t < 448; t += 256) {
      int c = div14(t), i = t - c * 14;
      int y = ybase + i;
      unsigned int o[7] = {0u, 0u, 0u, 0u, 0u, 0u, 0u};
      if ((unsigned)y < 128u) {
        const unsigned short* row = XVt + ((hc + c) << 16) + (b * 128 + y) * 128;
#pragma unroll
        for (int k = 0; k < 7; ++k) {
          int x0 = xbase + 2 * k, x1 = x0 + 1;
          unsigned int lo = ((unsigned)x0 < 128u) ? row[x0] : 0u;
          unsigned int hi = ((unsigned)x1 < 128u) ? row[x1] : 0u;
          o[k] = lo | (hi << 16);
        }
      }
      int base = c * 232 + i * 14;
#pragma unroll
      for (int k = 0; k < 7; ++k) *(unsigned int*)&sm.sVt[base + k * 2] = o[k];
    }
  }
  // ---- Q: pure 16B copy (PQ pre-folded); always in-bounds ----
  {
    int m = tid >> 2, seg = tid & 3;
    int pix = (b * 128 + wy * 8 + (m >> 3)) * 128 + wx * 8 + (m & 7);
    *(uint4*)&sm.sU[m * 40 + seg * 8] = *(const uint4*)&XQ[(pix << 8) + hc + seg * 8];
  }
  __syncthreads();  // the only barrier

  // ---- S = Q K^T ----
  bf16x8 aq = *(const bf16x8*)&sm.sU[(wave * 16 + r) * 40 + q * 8];
  f32x4 s[14];
#pragma unroll
  for (int nt = 0; nt < 14; ++nt) {
    bf16x8 bk = *(const bf16x8*)&sm.sK[(nt * 16 + r) * 40 + q * 8];
    f32x4 z = {0.f, 0.f, 0.f, 0.f};
    s[nt] = __builtin_amdgcn_mfma_f32_16x16x32_bf16(aq, bk, z, 0, 0, 0);
  }
  if (interior) {
#pragma unroll
    for (int nt = 0; nt < 12; ++nt)
#pragma unroll
      for (int g = 0; g < 4; ++g) s[nt][g] *= SCALE;
#pragma unroll
    for (int g = 0; g < 4; ++g) {
      s[12][g] = (r < 4) ? s[12][g] * SCALE : -1e30f;
      s[13][g] = -1e30f;
    }
  } else {
#pragma unroll
    for (int nt = 0; nt < 14; ++nt) {
      int n = nt * 16 + r;
      int i = div14(n), j = n - i * 14;
      int y = ybase + i, x = xbase + j;
      bool valid = (n < 196) && ((unsigned)y < 128u) && ((unsigned)x < 128u);
#pragma unroll
      for (int g = 0; g < 4; ++g) s[nt][g] = valid ? s[nt][g] * SCALE : -1e30f;
    }
  }
  // ---- softmax (rows in registers; 16-lane group reduce) ----
  float mx[4] = {-1e30f, -1e30f, -1e30f, -1e30f};
#pragma unroll
  for (int nt = 0; nt < 14; ++nt)
#pragma unroll
    for (int g = 0; g < 4; ++g) mx[g] = fmaxf(mx[g], s[nt][g]);
#pragma unroll
  for (int d = 1; d < 16; d <<= 1)
#pragma unroll
    for (int g = 0; g < 4; ++g) mx[g] = fmaxf(mx[g], __shfl_xor(mx[g], d));
  float sum[4] = {0.f, 0.f, 0.f, 0.f};
#pragma unroll
  for (int nt = 0; nt < 14; ++nt)
#pragma unroll
    for (int g = 0; g < 4; ++g) {
      float e = __expf(s[nt][g] - mx[g]);
      s[nt][g] = e; sum[g] += e;
    }
#pragma unroll
  for (int d = 1; d < 16; d <<= 1)
#pragma unroll
    for (int g = 0; g < 4; ++g) sum[g] += __shfl_xor(sum[g], d);
  float inv[4];
#pragma unroll
  for (int g = 0; g < 4; ++g) inv[g] = 1.f / sum[g];
#pragma unroll
  for (int nt = 0; nt < 14; ++nt)
#pragma unroll
    for (int g = 0; g < 4; ++g) s[nt][g] *= inv[g];

  // ---- O = P @ V (P transits sU; wave-private rows -> no barriers) ----
  f32x4 ov[2];
  ov[0] = (f32x4){0.f, 0.f, 0.f, 0.f}; ov[1] = ov[0];
#pragma unroll
  for (int ck = 0; ck < 7; ++ck) {
#pragma unroll
    for (int tq = 0; tq < 2; ++tq)
#pragma unroll
      for (int g = 0; g < 4; ++g)
        sm.sU[(wave * 16 + q * 4 + g) * 40 + tq * 16 + r] = f2bf(s[ck * 2 + tq][g]);
    bf16x8 ap = *(const bf16x8*)&sm.sU[(wave * 16 + r) * 40 + q * 8];
#pragma unroll
    for (int t2 = 0; t2 < 2; ++t2) {
      bf16x8 bv = *(const bf16x8*)&sm.sVt[(t2 * 16 + r) * 232 + ck * 32 + q * 8];
      ov[t2] = __builtin_amdgcn_mfma_f32_16x16x32_bf16(ap, bv, ov[t2], 0, 0, 0);
    }
  }
  // ---- write O_h to global (via sU for vectorized stores; wave-local rows) ----
#pragma unroll
  for (int t2 = 0; t2 < 2; ++t2)
#pragma unroll
    for (int g = 0; g < 4; ++g)
      sm.sU[(wave * 16 + q * 4 + g) * 40 + t2 * 16 + r] = f2bf(ov[t2][g]);
  {
    int m = tid >> 2, seg = tid & 3;
    int pix = (b * 128 + wy * 8 + (m >> 3)) * 128 + wx * 8 + (m & 7);
    bf16x8 o8 = *(const bf16x8*)&sm.sU[m * 40 + seg * 8];
    *(uint4*)&XO[(pix << 8) + hc + seg * 8] = *(uint4*)&o8;
  }
}

// ---------------- out_proj: out = XO @ Wp + bias (f32) ----------------
__global__ __launch_bounds__(256, 2) void out_proj_kernel(
    const unsigned short* __restrict__ XO, const unsigned short* __restrict__ Wtp,
    const float* __restrict__ bp, float* __restrict__ out) {
  __shared__ unsigned short sA[128 * 72];
  const int m0 = blockIdx.x << 7;
  const int tid = threadIdx.x;
  const int wave = tid >> 6, lane = tid & 63, q = lane >> 4, r = lane & 15;

  f32x4 acc[2][16];
#pragma unroll
  for (int nt = 0; nt < 16; ++nt) {
    float bv = bp[nt * 16 + r];
    acc[0][nt] = (f32x4){bv, bv, bv, bv};
    acc[1][nt] = (f32x4){bv, bv, bv, bv};
  }
  for (int cc = 0; cc < 4; ++cc) {
    __syncthreads();
    for (int t = tid; t < 1024; t += 256) {
      int row = t >> 3, seg = t & 7;
      *(uint4*)&sA[row * 72 + seg * 8] =
          *(const uint4*)&XO[((m0 + row) << 8) + cc * 64 + seg * 8];
    }
    __syncthreads();
#pragma unroll
    for (int kk = 0; kk < 2; ++kk) {
      const int k0 = cc * 64 + kk * 32;
      bf16x8 a0 = *(const bf16x8*)&sA[(wave * 32 + r) * 72 + kk * 32 + q * 8];
      bf16x8 a1 = *(const bf16x8*)&sA[(wave * 32 + 16 + r) * 72 + kk * 32 + q * 8];
#pragma unroll
      for (int nt = 0; nt < 16; ++nt) {
        bf16x8 bw = *(const bf16x8*)&Wtp[((nt * 16 + r) << 8) + k0 + q * 8];
        acc[0][nt] = __builtin_amdgcn_mfma_f32_16x16x32_bf16(a0, bw, acc[0][nt], 0, 0, 0);
        acc[1][nt] = __builtin_amdgcn_mfma_f32_16x16x32_bf16(a1, bw, acc[1][nt], 0, 0, 0);
      }
    }
  }
#pragma unroll
  for (int mt = 0; mt < 2; ++mt)
#pragma unroll
    for (int nt = 0; nt < 16; ++nt)
#pragma unroll
      for (int g = 0; g < 4; ++g) {
        int row = m0 + wave * 32 + mt * 16 + q * 4 + g;
        out[(row << 8) + nt * 16 + r] = acc[mt][nt][g];
      }
}

extern "C" void kernel_launch(void* const* d_in, const int* in_sizes, int n_in,
                              void* d_out, int out_size, void* d_ws, size_t ws_size,
                              hipStream_t stream) {
  (void)in_sizes; (void)n_in; (void)out_size; (void)ws_size;
  const float* xg = (const float*)d_in[0];
  const float* Wq = (const float*)d_in[1];
  const float* Wk = (const float*)d_in[2];
  const float* Wv = (const float*)d_in[3];
  const float* Wp = (const float*)d_in[4];
  const float* bp = (const float*)d_in[5];
  float* out = (float*)d_out;

  // ws layout (bytes), NEED = 101466112 (== round-3 check, proven available):
  //   XQO 0..33554432 (XQpos, later overwritten in-place as XO)
  //   XK  33554432..67108864
  //   XVt 67108864..100663296   ([ch][pix] transposed)
  //   Wt4 100663296..101187584
  //   PK  101187584..101400576
  //   PQ  101400576..101466112
  char* ws = (char*)d_ws;
  unsigned short* XQO = (unsigned short*)(ws);
  unsigned short* XK  = (unsigned short*)(ws + 33554432u);
  unsigned short* XVt = (unsigned short*)(ws + 67108864u);
  unsigned short* Wt4 = (unsigned short*)(ws + 100663296u);
  float* PK = (float*)(ws + 101187584u);
  float* PQ = (float*)(ws + 101400576u);

  pos_proj_kernel<<<dim3(272), dim3(256), 0, stream>>>(Wq, Wk, PK, PQ);
  wtrans_kernel<<<dim3(1024), dim3(256), 0, stream>>>(Wq, Wk, Wv, Wp, Wt4);
  qkv_gemm_kernel<<<dim3(3, 512), dim3(256), 0, stream>>>(xg, Wt4, PQ, XQO, XK, XVt);
  halo_kernel<<<dim3(8192), dim3(256), 0, stream>>>(XQO, XK, XVt, PK, XQO);
  out_proj_kernel<<<dim3(512), dim3(256), 0, stream>>>(XQO, Wt4 + 3 * 65536, bp, out);
}

// Round 5
// 355.490 us; speedup vs baseline: 1.1872x; 1.1872x over previous
//
#include <hip/hip_runtime.h>

// HaloAttn on MI355X (gfx950). f32 in/out, bf16 MFMA internals.
// Pipeline (ws >= 101,466,112 B, proven available in rounds 3-4):
//   pos_proj:  PK [208][256] f32, PQ [64][256] f32
//   wtrans2:   Wt'[mat][kc][n][32] bf16 — k-chunked transposed weights (contiguous B-tiles)
//   qkv_gemm:  XQpos = x@Wq + PQ (bf16), XK = x@Wk (bf16), XVt = (x@Wv)^T [ch][pix] (bf16)
//              B-tiles staged via LDS; XVt stored via LDS transpose (coalesced)
//   halo:      one WG per (window, head) — unchanged from round 4
//   out_proj:  out = XO @ Wp + bias (f32), B-tiles via LDS

using bf16x8 = __attribute__((ext_vector_type(8))) short;
using f32x4  = __attribute__((ext_vector_type(4))) float;

__device__ __forceinline__ float bf2f(unsigned short u) {
  return __uint_as_float(((unsigned int)u) << 16);
}
__device__ __forceinline__ unsigned short f2bf(float f) {
  unsigned int x = __float_as_uint(f);
  x += 0x7fffu + ((x >> 16) & 1u);
  return (unsigned short)(x >> 16);
}
__device__ __forceinline__ unsigned int pack2(float a, float b) {
  return (unsigned int)f2bf(a) | ((unsigned int)f2bf(b) << 16);
}
__device__ __forceinline__ int div14(int p) { return (p * 4682) >> 16; }

// ---------------- pos_proj ----------------
__global__ __launch_bounds__(256) void pos_proj_kernel(
    const float* __restrict__ Wq, const float* __restrict__ Wk,
    float* __restrict__ PK, float* __restrict__ PQ) {
  __shared__ float pr[256];
  const int row = blockIdx.x, o = threadIdx.x;
  const float* Wm;
  float* dst;
  int ii, jj;
  if (row < 208) {
    if (row >= 196) { PK[row * 256 + o] = 0.f; return; }
    ii = row / 14; jj = row % 14;
    Wm = Wk; dst = PK + row * 256;
  } else {
    int qp = row - 208;
    ii = (qp >> 3) + 3; jj = (qp & 7) + 3;
    Wm = Wq; dst = PQ + qp * 256;
  }
  const int cl = o & 127, mfreq = cl >> 1;
  float t = powf(10000.f, (float)mfreq * (1.f / 64.f));
  float base = (o < 128) ? (float)(ii + 1) : (float)(jj + 1);
  float arg = base * (6.283185307179586f / 14.000001f) / t;
  pr[o] = (cl & 1) ? cosf(arg) : sinf(arg);
  __syncthreads();
  float acc = 0.f;
  for (int c = 0; c < 256; ++c) acc = fmaf(pr[c], Wm[c * 256 + o], acc);
  dst[o] = acc;
}

// ---------------- wtrans2: Wt'[mat][kc][n][32] = bf16(W[kc*32+kk][n]) ----------------
// grid 32 = mat*8 + kc. Coalesced read (over n), LDS transpose, coalesced write.
__global__ __launch_bounds__(256) void wtrans2_kernel(
    const float* __restrict__ Wq, const float* __restrict__ Wk,
    const float* __restrict__ Wv, const float* __restrict__ Wp,
    unsigned short* __restrict__ Wt) {
  __shared__ unsigned short sW[256 * 40];  // [n][kk], pad 40
  const int mat = blockIdx.x >> 3, kc = blockIdx.x & 7;
  const float* src = (mat == 0) ? Wq : (mat == 1) ? Wk : (mat == 2) ? Wv : Wp;
  const int tid = threadIdx.x;
  for (int t = tid; t < 2048; t += 256) {
    int k = t >> 6, sg = t & 63;
    float4 v = *(const float4*)&src[(kc * 32 + k) * 256 + sg * 4];
    sW[(sg * 4 + 0) * 40 + k] = f2bf(v.x);
    sW[(sg * 4 + 1) * 40 + k] = f2bf(v.y);
    sW[(sg * 4 + 2) * 40 + k] = f2bf(v.z);
    sW[(sg * 4 + 3) * 40 + k] = f2bf(v.w);
  }
  __syncthreads();
  unsigned short* dst = Wt + mat * 65536 + kc * 8192;
  for (int t = tid; t < 1024; t += 256) {
    int n = t >> 2, sg = t & 3;
    *(uint4*)&dst[n * 32 + sg * 8] = *(const uint4*)&sW[n * 40 + sg * 8];
  }
}

// ---------------- qkv_gemm: grid (3, 512); M=128, N=256, K in 8 chunks of 32 ----------------
struct QkvLds {
  union {
    struct {
      unsigned short sA[128 * 40];  // A-tile bf16 [row][k32], stride 40
      unsigned short sB[256 * 40];  // B-tile bf16 [n][k32], stride 40
    } s;
    unsigned short sT[64 * 136];    // V-transpose chunk [ch64][pix128], stride 136
  } u;
  float sPQ[8 * 256];               // PQ slice (mat 0 only)
};

__global__ __launch_bounds__(256, 2) void qkv_gemm_kernel(
    const float* __restrict__ xg, const unsigned short* __restrict__ Wt,
    const float* __restrict__ PQ,
    unsigned short* __restrict__ XQ, unsigned short* __restrict__ XK,
    unsigned short* __restrict__ XVt) {
  __shared__ QkvLds sm;
  const int mat = blockIdx.x, m0 = blockIdx.y << 7;
  const int tid = threadIdx.x;
  const int wave = tid >> 6, lane = tid & 63, q = lane >> 4, r = lane & 15;
  const unsigned short* Wb = Wt + mat * 65536;

  if (mat == 0) {  // stage PQ rows (y&7)*8 .. +8 (one image row per WG -> y fixed)
    const int y7 = (m0 >> 7) & 7;
    const float* srcp = PQ + (y7 * 8) * 256;
    for (int t = tid; t < 512; t += 256)
      *(float4*)&sm.sPQ[t * 4] = *(const float4*)&srcp[t * 4];
  }

  f32x4 acc[2][16];
#pragma unroll
  for (int mt = 0; mt < 2; ++mt)
#pragma unroll
    for (int nt = 0; nt < 16; ++nt) acc[mt][nt] = (f32x4){0.f, 0.f, 0.f, 0.f};

  for (int kc = 0; kc < 8; ++kc) {
    __syncthreads();
    // stage A: x[m0..+127][kc*32..+31] f32 -> bf16 (128B per row read)
    for (int t = tid; t < 512; t += 256) {
      int row = t >> 2, seg = t & 3;
      const float* src = xg + ((m0 + row) << 8) + kc * 32 + seg * 8;
      float4 f0 = *(const float4*)(src);
      float4 f1 = *(const float4*)(src + 4);
      uint4 w;
      w.x = pack2(f0.x, f0.y); w.y = pack2(f0.z, f0.w);
      w.z = pack2(f1.x, f1.y); w.w = pack2(f1.z, f1.w);
      *(uint4*)&sm.u.s.sA[row * 40 + seg * 8] = w;
    }
    // stage B: contiguous 16 KB chunk of Wt' -> sB
    {
      const unsigned short* src = Wb + kc * 8192;
      for (int t = tid; t < 1024; t += 256) {
        int n = t >> 2, sg = t & 3;
        *(uint4*)&sm.u.s.sB[n * 40 + sg * 8] = *(const uint4*)&src[t * 8];
      }
    }
    __syncthreads();
    bf16x8 a0 = *(const bf16x8*)&sm.u.s.sA[(wave * 32 + r) * 40 + q * 8];
    bf16x8 a1 = *(const bf16x8*)&sm.u.s.sA[(wave * 32 + 16 + r) * 40 + q * 8];
#pragma unroll
    for (int nt = 0; nt < 16; ++nt) {
      bf16x8 bw = *(const bf16x8*)&sm.u.s.sB[(nt * 16 + r) * 40 + q * 8];
      acc[0][nt] = __builtin_amdgcn_mfma_f32_16x16x32_bf16(a0, bw, acc[0][nt], 0, 0, 0);
      acc[1][nt] = __builtin_amdgcn_mfma_f32_16x16x32_bf16(a1, bw, acc[1][nt], 0, 0, 0);
    }
  }

  if (mat == 2) {
    // V transposed store via LDS: chunks of 64 channels, coalesced 256B rows
    __syncthreads();  // all LDS frag reads done before sT overwrite
#pragma unroll
    for (int c4 = 0; c4 < 4; ++c4) {
      if (c4) __syncthreads();
#pragma unroll
      for (int mt = 0; mt < 2; ++mt)
#pragma unroll
        for (int n4 = 0; n4 < 4; ++n4)
#pragma unroll
          for (int g = 0; g < 4; ++g) {
            int ch = n4 * 16 + r;
            int pr = wave * 32 + mt * 16 + q * 4 + g;
            sm.u.sT[ch * 136 + pr] = f2bf(acc[mt][c4 * 4 + n4][g]);
          }
      __syncthreads();
      for (int t = tid; t < 1024; t += 256) {
        int ch = t >> 4, sg = t & 15;
        *(uint4*)&XVt[((c4 * 64 + ch) << 16) + m0 + sg * 8] =
            *(const uint4*)&sm.u.sT[ch * 136 + sg * 8];
      }
    }
  } else {
    unsigned short* dst = (mat == 0) ? XQ : XK;
#pragma unroll
    for (int mt = 0; mt < 2; ++mt)
#pragma unroll
      for (int nt = 0; nt < 16; ++nt)
#pragma unroll
        for (int g = 0; g < 4; ++g) {
          int lrow = wave * 32 + mt * 16 + q * 4 + g;
          float v = acc[mt][nt][g];
          if (mat == 0) v += sm.sPQ[(lrow & 7) * 256 + nt * 16 + r];
          dst[((m0 + lrow) << 8) + nt * 16 + r] = f2bf(v);
        }
  }
}

// ---------------- halo: one WG per (window, head); grid 8192 (unchanged r4) ----------------
struct alignas(16) SMH {
  unsigned short sK[196 * 40];
  unsigned short sVt[32 * 232];
  unsigned short sU[64 * 40];
};

__global__ __launch_bounds__(256, 4) void halo_kernel(
    const unsigned short* XQ,           // aliases XO
    const unsigned short* __restrict__ XK,
    const unsigned short* __restrict__ XVt,
    const float* __restrict__ PK,
    unsigned short* XO) {
  __shared__ SMH sm;
  const int wid = blockIdx.x;
  const int h = wid & 7, win = wid >> 3;
  const int b = win >> 8, widx = win & 255;
  const int wy = widx >> 4, wx = widx & 15;
  const int hc = h * 32;
  const int tid = threadIdx.x;
  const int wave = tid >> 6, lane = tid & 63, q = lane >> 4, r = lane & 15;
  const bool interior = (unsigned)(wy - 1) < 14u && (unsigned)(wx - 1) < 14u;
  const int ybase = wy * 8 - 3, xbase = wx * 8 - 3;
  constexpr float SCALE = 0.17677669529663687f;

  for (int idx = tid; idx < 1152; idx += 256) {
    int rr = idx / 36, c2 = idx - rr * 36;
    sm.sVt[rr * 232 + 196 + c2] = 0;
  }

  if (interior) {
    for (int t = tid; t < 784; t += 256) {
      int p = t >> 2, seg = t & 3;
      int i = div14(p), j = p - i * 14;
      int pix = (b * 128 + ybase + i) * 128 + xbase + j;
      bf16x8 kv = *(const bf16x8*)&XK[(pix << 8) + hc + seg * 8];
      const float4* pk4 = (const float4*)(PK + (p << 8) + hc + seg * 8);
      float4 f0 = pk4[0], f1 = pk4[1];
      uint4 w;
      w.x = pack2(bf2f((unsigned short)kv[0]) + f0.x, bf2f((unsigned short)kv[1]) + f0.y);
      w.y = pack2(bf2f((unsigned short)kv[2]) + f0.z, bf2f((unsigned short)kv[3]) + f0.w);
      w.z = pack2(bf2f((unsigned short)kv[4]) + f1.x, bf2f((unsigned short)kv[5]) + f1.y);
      w.w = pack2(bf2f((unsigned short)kv[6]) + f1.z, bf2f((unsigned short)kv[7]) + f1.w);
      *(uint4*)&sm.sK[p * 40 + seg * 8] = w;
    }
    for (int t = tid; t < 448; t += 256) {
      int c = div14(t), i = t - c * 14;
      int pix0 = (b * 128 + ybase + i) * 128 + xbase;
      const unsigned int* src = (const unsigned int*)(XVt + ((hc + c) << 16) + pix0 - 1);
      unsigned int d[8];
#pragma unroll
      for (int k = 0; k < 8; ++k) d[k] = src[k];
      int base = c * 232 + i * 14;
#pragma unroll
      for (int k = 0; k < 7; ++k)
        *(unsigned int*)&sm.sVt[base + k * 2] = (d[k] >> 16) | (d[k + 1] << 16);
    }
  } else {
    for (int t = tid; t < 784; t += 256) {
      int p = t >> 2, seg = t & 3;
      int i = div14(p), j = p - i * 14;
      int y = ybase + i, x = xbase + j;
      uint4 w = {0u, 0u, 0u, 0u};
      if ((unsigned)y < 128u && (unsigned)x < 128u) {
        int pix = (b * 128 + y) * 128 + x;
        bf16x8 kv = *(const bf16x8*)&XK[(pix << 8) + hc + seg * 8];
        const float4* pk4 = (const float4*)(PK + (p << 8) + hc + seg * 8);
        float4 f0 = pk4[0], f1 = pk4[1];
        w.x = pack2(bf2f((unsigned short)kv[0]) + f0.x, bf2f((unsigned short)kv[1]) + f0.y);
        w.y = pack2(bf2f((unsigned short)kv[2]) + f0.z, bf2f((unsigned short)kv[3]) + f0.w);
        w.z = pack2(bf2f((unsigned short)kv[4]) + f1.x, bf2f((unsigned short)kv[5]) + f1.y);
        w.w = pack2(bf2f((unsigned short)kv[6]) + f1.z, bf2f((unsigned short)kv[7]) + f1.w);
      }
      *(uint4*)&sm.sK[p * 40 + seg * 8] = w;
    }
    for (int t = tid; t < 448; t += 256) {
      int c = div14(t), i = t - c * 14;
      int y = ybase + i;
      unsigned int o[7] = {0u, 0u, 0u, 0u, 0u, 0u, 0u};
      if ((unsigned)y < 128u) {
        const unsigned short* row = XVt + ((hc + c) << 16) + (b * 128 + y) * 128;
#pragma unroll
        for (int k = 0; k < 7; ++k) {
          int x0 = xbase + 2 * k, x1 = x0 + 1;
          unsigned int lo = ((unsigned)x0 < 128u) ? row[x0] : 0u;
          unsigned int hi = ((unsigned)x1 < 128u) ? row[x1] : 0u;
          o[k] = lo | (hi << 16);
        }
      }
      int base = c * 232 + i * 14;
#pragma unroll
      for (int k = 0; k < 7; ++k) *(unsigned int*)&sm.sVt[base + k * 2] = o[k];
    }
  }
  {
    int m = tid >> 2, seg = tid & 3;
    int pix = (b * 128 + wy * 8 + (m >> 3)) * 128 + wx * 8 + (m & 7);
    *(uint4*)&sm.sU[m * 40 + seg * 8] = *(const uint4*)&XQ[(pix << 8) + hc + seg * 8];
  }
  __syncthreads();

  bf16x8 aq = *(const bf16x8*)&sm.sU[(wave * 16 + r) * 40 + q * 8];
  f32x4 s[14];
#pragma unroll
  for (int nt = 0; nt < 14; ++nt) {
    bf16x8 bk = *(const bf16x8*)&sm.sK[(nt * 16 + r) * 40 + q * 8];
    f32x4 z = {0.f, 0.f, 0.f, 0.f};
    s[nt] = __builtin_amdgcn_mfma_f32_16x16x32_bf16(aq, bk, z, 0, 0, 0);
  }
  if (interior) {
#pragma unroll
    for (int nt = 0; nt < 12; ++nt)
#pragma unroll
      for (int g = 0; g < 4; ++g) s[nt][g] *= SCALE;
#pragma unroll
    for (int g = 0; g < 4; ++g) {
      s[12][g] = (r < 4) ? s[12][g] * SCALE : -1e30f;
      s[13][g] = -1e30f;
    }
  } else {
#pragma unroll
    for (int nt = 0; nt < 14; ++nt) {
      int n = nt * 16 + r;
      int i = div14(n), j = n - i * 14;
      int y = ybase + i, x = xbase + j;
      bool valid = (n < 196) && ((unsigned)y < 128u) && ((unsigned)x < 128u);
#pragma unroll
      for (int g = 0; g < 4; ++g) s[nt][g] = valid ? s[nt][g] * SCALE : -1e30f;
    }
  }
  float mx[4] = {-1e30f, -1e30f, -1e30f, -1e30f};
#pragma unroll
  for (int nt = 0; nt < 14; ++nt)
#pragma unroll
    for (int g = 0; g < 4; ++g) mx[g] = fmaxf(mx[g], s[nt][g]);
#pragma unroll
  for (int d = 1; d < 16; d <<= 1)
#pragma unroll
    for (int g = 0; g < 4; ++g) mx[g] = fmaxf(mx[g], __shfl_xor(mx[g], d));
  float sum[4] = {0.f, 0.f, 0.f, 0.f};
#pragma unroll
  for (int nt = 0; nt < 14; ++nt)
#pragma unroll
    for (int g = 0; g < 4; ++g) {
      float e = __expf(s[nt][g] - mx[g]);
      s[nt][g] = e; sum[g] += e;
    }
#pragma unroll
  for (int d = 1; d < 16; d <<= 1)
#pragma unroll
    for (int g = 0; g < 4; ++g) sum[g] += __shfl_xor(sum[g], d);
  float inv[4];
#pragma unroll
  for (int g = 0; g < 4; ++g) inv[g] = 1.f / sum[g];
#pragma unroll
  for (int nt = 0; nt < 14; ++nt)
#pragma unroll
    for (int g = 0; g < 4; ++g) s[nt][g] *= inv[g];

  f32x4 ov[2];
  ov[0] = (f32x4){0.f, 0.f, 0.f, 0.f}; ov[1] = ov[0];
#pragma unroll
  for (int ck = 0; ck < 7; ++ck) {
#pragma unroll
    for (int tq = 0; tq < 2; ++tq)
#pragma unroll
      for (int g = 0; g < 4; ++g)
        sm.sU[(wave * 16 + q * 4 + g) * 40 + tq * 16 + r] = f2bf(s[ck * 2 + tq][g]);
    bf16x8 ap = *(const bf16x8*)&sm.sU[(wave * 16 + r) * 40 + q * 8];
#pragma unroll
    for (int t2 = 0; t2 < 2; ++t2) {
      bf16x8 bv = *(const bf16x8*)&sm.sVt[(t2 * 16 + r) * 232 + ck * 32 + q * 8];
      ov[t2] = __builtin_amdgcn_mfma_f32_16x16x32_bf16(ap, bv, ov[t2], 0, 0, 0);
    }
  }
#pragma unroll
  for (int t2 = 0; t2 < 2; ++t2)
#pragma unroll
    for (int g = 0; g < 4; ++g)
      sm.sU[(wave * 16 + q * 4 + g) * 40 + t2 * 16 + r] = f2bf(ov[t2][g]);
  {
    int m = tid >> 2, seg = tid & 3;
    int pix = (b * 128 + wy * 8 + (m >> 3)) * 128 + wx * 8 + (m & 7);
    bf16x8 o8 = *(const bf16x8*)&sm.sU[m * 40 + seg * 8];
    *(uint4*)&XO[(pix << 8) + hc + seg * 8] = *(uint4*)&o8;
  }
}

// ---------------- out_proj: out = XO @ Wp + bias (f32); B via LDS ----------------
__global__ __launch_bounds__(256, 2) void out_proj_kernel(
    const unsigned short* __restrict__ XO, const unsigned short* __restrict__ Wt,
    const float* __restrict__ bp, float* __restrict__ out) {
  __shared__ unsigned short sA[128 * 40];
  __shared__ unsigned short sB[256 * 40];
  const int m0 = blockIdx.x << 7;
  const int tid = threadIdx.x;
  const int wave = tid >> 6, lane = tid & 63, q = lane >> 4, r = lane & 15;
  const unsigned short* Wb = Wt + 3 * 65536;  // Wproj chunked

  f32x4 acc[2][16];
#pragma unroll
  for (int nt = 0; nt < 16; ++nt) {
    float bv = bp[nt * 16 + r];
    acc[0][nt] = (f32x4){bv, bv, bv, bv};
    acc[1][nt] = (f32x4){bv, bv, bv, bv};
  }
  for (int kc = 0; kc < 8; ++kc) {
    __syncthreads();
    for (int t = tid; t < 512; t += 256) {
      int row = t >> 2, seg = t & 3;
      *(uint4*)&sA[row * 40 + seg * 8] =
          *(const uint4*)&XO[((m0 + row) << 8) + kc * 32 + seg * 8];
    }
    {
      const unsigned short* src = Wb + kc * 8192;
      for (int t = tid; t < 1024; t += 256) {
        int n = t >> 2, sg = t & 3;
        *(uint4*)&sB[n * 40 + sg * 8] = *(const uint4*)&src[t * 8];
      }
    }
    __syncthreads();
    bf16x8 a0 = *(const bf16x8*)&sA[(wave * 32 + r) * 40 + q * 8];
    bf16x8 a1 = *(const bf16x8*)&sA[(wave * 32 + 16 + r) * 40 + q * 8];
#pragma unroll
    for (int nt = 0; nt < 16; ++nt) {
      bf16x8 bw = *(const bf16x8*)&sB[(nt * 16 + r) * 40 + q * 8];
      acc[0][nt] = __builtin_amdgcn_mfma_f32_16x16x32_bf16(a0, bw, acc[0][nt], 0, 0, 0);
      acc[1][nt] = __builtin_amdgcn_mfma_f32_16x16x32_bf16(a1, bw, acc[1][nt], 0, 0, 0);
    }
  }
#pragma unroll
  for (int mt = 0; mt < 2; ++mt)
#pragma unroll
    for (int nt = 0; nt < 16; ++nt)
#pragma unroll
      for (int g = 0; g < 4; ++g) {
        int row = m0 + wave * 32 + mt * 16 + q * 4 + g;
        out[(row << 8) + nt * 16 + r] = acc[mt][nt][g];
      }
}

extern "C" void kernel_launch(void* const* d_in, const int* in_sizes, int n_in,
                              void* d_out, int out_size, void* d_ws, size_t ws_size,
                              hipStream_t stream) {
  (void)in_sizes; (void)n_in; (void)out_size; (void)ws_size;
  const float* xg = (const float*)d_in[0];
  const float* Wq = (const float*)d_in[1];
  const float* Wk = (const float*)d_in[2];
  const float* Wv = (const float*)d_in[3];
  const float* Wp = (const float*)d_in[4];
  const float* bp = (const float*)d_in[5];
  float* out = (float*)d_out;

  // ws layout (bytes), NEED = 101466112 (proven available rounds 3-4):
  //   XQO 0..33554432 | XK ..67108864 | XVt ..100663296 | Wt' ..101187584
  //   PK ..101400576 | PQ ..101466112
  char* ws = (char*)d_ws;
  unsigned short* XQO = (unsigned short*)(ws);
  unsigned short* XK  = (unsigned short*)(ws + 33554432u);
  unsigned short* XVt = (unsigned short*)(ws + 67108864u);
  unsigned short* Wt  = (unsigned short*)(ws + 100663296u);
  float* PK = (float*)(ws + 101187584u);
  float* PQ = (float*)(ws + 101400576u);

  pos_proj_kernel<<<dim3(272), dim3(256), 0, stream>>>(Wq, Wk, PK, PQ);
  wtrans2_kernel<<<dim3(32), dim3(256), 0, stream>>>(Wq, Wk, Wv, Wp, Wt);
  qkv_gemm_kernel<<<dim3(3, 512), dim3(256), 0, stream>>>(xg, Wt, PQ, XQO, XK, XVt);
  halo_kernel<<<dim3(8192), dim3(256), 0, stream>>>(XQO, XK, XVt, PK, XQO);
  out_proj_kernel<<<dim3(512), dim3(256), 0, stream>>>(XQO, Wt, bp, out);
}